// Round 5
// baseline (276.902 us; speedup 1.0000x reference)
//
#include <hip/hip_runtime.h>
#include <math.h>

// Problem constants
#define T_  204
#define I_  5
#define H_  24
#define L_  10
#define O_  612
#define Bsz 8192

typedef _Float16 half8 __attribute__((ext_vector_type(8)));
typedef _Float16 half2t __attribute__((ext_vector_type(2)));
typedef float    float4t __attribute__((ext_vector_type(4)));

union U16B { float4t f4; half8 h8; float f[4]; _Float16 h[8]; half2t h2[4]; };

__device__ __forceinline__ float fast_rcp(float x){ return __builtin_amdgcn_rcpf(x); }
__device__ __forceinline__ float fast_ex2(float x){ return __builtin_amdgcn_exp2f(x); }
__device__ __forceinline__ half2t pk2(float a, float b){
    return __builtin_bit_cast(half2t, __builtin_amdgcn_cvt_pkrtz(a, b));
}

#define MFMA16(a,b,c) __builtin_amdgcn_mfma_f32_16x16x32_f16((a),(b),(c),0,0,0)

#define L2E  1.44269504f
#define L2E2 2.88539008f

// Unit owned by lane-quad q, tile T (q<3: 8q+T; q==3: overflow units 6,7,14,15,22,23)
__device__ __forceinline__ int unit_of(int q, int T) {
    return (q < 3) ? (8*q + T) : (8*(T >> 1) + 6 + (T & 1));
}

// Prepack fc0_w into per-timestep fp16 A-fragments (A[m=l][k=j], zeros elsewhere).
__global__ __launch_bounds__(64)
void pack_fc0(const float* __restrict__ fc0_w, float4t* __restrict__ dst)
{
    const int t = blockIdx.x, lane = threadIdx.x;
    const int m = lane & 15, q = lane >> 4;
    U16B v;
    #pragma unroll
    for (int i = 0; i < 8; ++i) {
        const int k = 8*q + i;
        float f = (m < L_ && k < H_) ? fc0_w[m*(T_*H_) + t*H_ + k] : 0.0f;
        v.h[i] = (_Float16)f;
    }
    dst[t*64 + lane] = v.f4;
}

// R16: R11-R15 fit wall ~= 2.4 x per-wave ISSUE cycles across all structures
// (issue-model: VALU 2cy, trans 8cy wave64). Per-instruction bubbles dominate;
// R12 proved a single in-order wave can't fill its own bubbles. With 512
// single-wave WGs we sit at 1 wave/SIMD -- zero hardware interleave. Fix: pack
// 8 INDEPENDENT batch-tiles into one 512-thread block (8 waves -> 2 per SIMD).
// HW round-robin fills one wave's stalls with the other's issue. Per-wave code
// identical to R15 (waves never communicate; shfl is intra-wave; LDS staging
// per-wave slice) -> bitwise-identical numerics.
__global__ __launch_bounds__(512)
void lstm_mfma(const float* __restrict__ x,
               const float* __restrict__ W_ih,
               const float* __restrict__ W_hh,
               const float* __restrict__ b_ih,
               const float* __restrict__ b_hh,
               const float* __restrict__ fc0_b,
               const float* __restrict__ out_w,
               const float* __restrict__ out_b,
               const float4t* __restrict__ fc0A,   // prepacked in d_ws
               float* __restrict__ out)
{
    __shared__ __align__(16) _Float16 actL[8][16*24];  // per-wave epilogue staging

    const int tid  = threadIdx.x;
    const int wv   = tid >> 6;      // wave id = which batch-16 tile
    const int lane = tid & 63;
    const int m = lane & 15;        // element col / A row-within-tile
    const int q = lane >> 4;        // quad
    const int elem = (blockIdx.x * 8 + wv) * 16 + m;

    const float4t zf4 = {0.f, 0.f, 0.f, 0.f};

    // ---- gate A-fragments ----
    half8 Ag[6];
    #pragma unroll
    for (int T6 = 0; T6 < 6; ++T6) {
        const int u = unit_of(m >> 2, T6);
        const int srow = (m & 3) * H_ + u;       // torch gate-major row
        float wv_[8];
        if (q < 3) {
            const float4t* pw = (const float4t*)(W_hh + srow*H_ + 8*q);
            float4t wa = pw[0], wb = pw[1];
            #pragma unroll
            for (int i = 0; i < 4; ++i) { wv_[i] = wa[i]; wv_[4+i] = wb[i]; }
        } else {
            #pragma unroll
            for (int i = 0; i < 8; ++i) wv_[i] = 0.f;
            #pragma unroll
            for (int i = 0; i < I_; ++i) wv_[i] = W_ih[srow*I_ + i];
            wv_[5] = b_ih[srow] + b_hh[srow];
        }
        U16B tw;
        #pragma unroll
        for (int i = 0; i < 8; ++i) tw.h[i] = (_Float16)wv_[i];
        Ag[T6] = tw.h8;
    }

    const float* xp = x + (size_t)elem * (T_*I_);

    // ---- initial B-frag [h=0 | x_0 | 1 | 0,0]; x prefetch ring (depth 2) ----
    U16B B;
    if (q == 3) {
        B.h2[0] = pk2(xp[0], xp[1]);
        B.h2[1] = pk2(xp[2], xp[3]);
        B.h2[2] = pk2(xp[4], 1.0f);
        B.h2[3] = pk2(0.f, 0.f);
    } else {
        B.f4 = zf4;
    }
    float xC[I_] = {0,0,0,0,0};              // x(t+1), consumed at iter bottom
    if (q == 3) {
        #pragma unroll
        for (int i = 0; i < I_; ++i) xC[i] = xp[I_ + i];
    }

    float c_[6] = {0,0,0,0,0,0};
    float4t accF = zf4;
    float4t fa = fc0A[lane];                 // fc0 frag for t=0

    // ================= time loop (no barriers, no LDS) =================
    for (int t = 0; t < T_; ++t) {
        // prefetches: x(t+2), fc0 frag t+1
        const int tn = (t + 1 < T_) ? t + 1 : t;
        const float4t fan = fc0A[tn*64 + lane];
        float xN[I_] = {0,0,0,0,0};
        if (q == 3) {
            const int tp2 = (t + 2 < T_) ? t + 2 : T_ - 1;
            const float* xq = xp + tp2*I_;
            #pragma unroll
            for (int i = 0; i < I_; ++i) xN[i] = xq[i];
        }

        // 6 gate MFMAs
        float4t D0 = MFMA16(Ag[0], B.h8, zf4);
        float4t D1 = MFMA16(Ag[1], B.h8, zf4);
        float4t D2 = MFMA16(Ag[2], B.h8, zf4);
        float4t D3 = MFMA16(Ag[3], B.h8, zf4);
        float4t D4 = MFMA16(Ag[4], B.h8, zf4);
        float4t D5 = MFMA16(Ag[5], B.h8, zf4);

        // fused-denominator cell update, phase-interleaved across 6 units
        float hh[6];
        {
            float4t D[6] = {D0, D1, D2, D3, D4, D5};
            float ei[6], ef[6], eg[6], eo[6];
            #pragma unroll
            for (int u = 0; u < 6; ++u) {
                ei[u] = fast_ex2(D[u][0] * -L2E);    // e^{-i}
                ef[u] = fast_ex2(D[u][1] * -L2E);    // e^{-f}
                eg[u] = fast_ex2(D[u][2] *  L2E2);   // e^{+2g}
                eo[u] = fast_ex2(D[u][3] * -L2E);    // e^{-o}
            }
            float R1[6], nm[6];
            #pragma unroll
            for (int u = 0; u < 6; ++u) {
                const float Dn1 = 1.f + ef[u];       // 1/sigm(f)
                const float Dn2 = 1.f + ei[u];       // 1/sigm(i)
                const float Dn3 = eg[u] + 1.f;       // tanh(g) denom
                const float G   = eg[u] - 1.f;       // tanh(g) numer
                const float P   = Dn2 * Dn3;
                R1[u] = fast_rcp(Dn1 * P);
                nm[u] = fmaf(c_[u], P, Dn1 * G);
            }
            float es[6];
            #pragma unroll
            for (int u = 0; u < 6; ++u) {
                c_[u] = nm[u] * R1[u];
                es[u] = fast_ex2(__builtin_fabsf(c_[u]) * -L2E2);  // e^{-2|c'|}
            }
            #pragma unroll
            for (int u = 0; u < 6; ++u) {
                const float R2 = fast_rcp((1.f + eo[u]) * (1.f + es[u]));
                hh[u] = __builtin_copysignf((1.f - es[u]) * R2, c_[u]);
            }
        }

        // pack own h pairs; q3's pairs are the overflow units consumers need
        const float P0 = __builtin_bit_cast(float, pk2(hh[0], hh[1]));
        const float P1 = __builtin_bit_cast(float, pk2(hh[2], hh[3]));
        const float P2 = __builtin_bit_cast(float, pk2(hh[4], hh[5]));

        // fetch overflow pair from lane (m, q=3) = wave-lane 48+m (intra-wave)
        const int src = 48 + m;
        const float r0 = __shfl(P0, src, 64);
        const float r1 = __shfl(P1, src, 64);
        const float r2 = __shfl(P2, src, 64);
        const float rcv = (q == 0) ? r0 : ((q == 1) ? r1 : r2);

        // rebuild B-frag
        if (q < 3) {
            B.h2[0] = __builtin_bit_cast(half2t, P0);   // units 8q+0,1
            B.h2[1] = __builtin_bit_cast(half2t, P1);   // units 8q+2,3
            B.h2[2] = __builtin_bit_cast(half2t, P2);   // units 8q+4,5
            B.h2[3] = __builtin_bit_cast(half2t, rcv);  // units 8q+6,7 (from q3)
        } else {
            B.h2[0] = pk2(xC[0], xC[1]);
            B.h2[1] = pk2(xC[2], xC[3]);
            B.h2[2] = pk2(xC[4], 1.0f);
            B.h2[3] = pk2(0.f, 0.f);
        }

        // fc0 accumulation with h_t (fc0A rows k>=24 are zero)
        U16B fF; fF.f4 = fa;
        accF = MFMA16(fF.h8, B.h8, accF);

        fa = fan;
        #pragma unroll
        for (int i = 0; i < I_; ++i) xC[i] = xN[i];
    }

    // ================= epilogue (validated R7/R8; per-wave LDS slice) ======
    float av[4];
    #pragma unroll
    for (int r = 0; r < 4; ++r) {
        const int l = 4*q + r;
        const float fb = (l < L_) ? fc0_b[l] : 0.f;
        const float v = accF[r] + fb;
        av[r] = (l < L_) ? fmaxf(v, 0.f) : 0.f;
    }
    *(half2t*)(&actL[wv][m*24 + 4*q])     = pk2(av[0], av[1]);
    *(half2t*)(&actL[wv][m*24 + 4*q + 2]) = pk2(av[2], av[3]);
    __builtin_amdgcn_wave_barrier();

    U16B Ba;
    if (q < 2) Ba.f4 = *(const float4t*)(&actL[wv][m*24 + q*8]);
    else       Ba.f4 = zf4;            // k>=16 unused (out_w A-frag zero there)

    for (int Tt = 0; Tt < 39; ++Tt) {
        const int row = 16*Tt + m;
        float w0=0.f,w1=0.f,w2=0.f,w3=0.f,w4=0.f,w5=0.f,w6=0.f,w7=0.f;
        if (row < O_ && q < 2) {
            const float2* p2 = (const float2*)(out_w + row*L_);
            if (q == 0) {
                float2 a = p2[0], b = p2[1], cc = p2[2], dd = p2[3];
                w0=a.x; w1=a.y; w2=b.x; w3=b.y; w4=cc.x; w5=cc.y; w6=dd.x; w7=dd.y;
            } else {
                float2 a = p2[4];
                w0=a.x; w1=a.y;
            }
        }
        U16B Aw;
        Aw.h2[0] = pk2(w0,w1); Aw.h2[1] = pk2(w2,w3);
        Aw.h2[2] = pk2(w4,w5); Aw.h2[3] = pk2(w6,w7);

        float4t dd = MFMA16(Aw.h8, Ba.h8, zf4);

        const int ob = 16*Tt + 4*q;
        if (ob < O_) {
            const float4t bias = *(const float4t*)(out_b + ob);
            #pragma unroll
            for (int r = 0; r < 4; ++r) dd[r] += bias[r];
            *(float4t*)(out + (size_t)elem*O_ + ob) = dd;
        }
    }
}

extern "C" void kernel_launch(void* const* d_in, const int* in_sizes, int n_in,
                              void* d_out, int out_size, void* d_ws, size_t ws_size,
                              hipStream_t stream)
{
    const float* x     = (const float*)d_in[0];
    const float* W_ih  = (const float*)d_in[1];
    const float* W_hh  = (const float*)d_in[2];
    const float* b_ih  = (const float*)d_in[3];
    const float* b_hh  = (const float*)d_in[4];
    const float* fc0_w = (const float*)d_in[5];
    const float* fc0_b = (const float*)d_in[6];
    const float* out_w = (const float*)d_in[7];
    const float* out_b = (const float*)d_in[8];
    float* out = (float*)d_out;
    (void)ws_size;

    pack_fc0<<<dim3(T_), dim3(64), 0, stream>>>(fc0_w, (float4t*)d_ws);
    lstm_mfma<<<dim3(Bsz/(16*8)), dim3(512), 0, stream>>>(
        x, W_ih, W_hh, b_ih, b_hh, fc0_b, out_w, out_b,
        (const float4t*)d_ws, out);
}

// Round 6
// 273.367 us; speedup vs baseline: 1.0129x; 1.0129x over previous
//
#include <hip/hip_runtime.h>
#include <math.h>

// Problem constants
#define T_  204
#define I_  5
#define H_  24
#define L_  10
#define O_  612
#define Bsz 8192

typedef _Float16 half8 __attribute__((ext_vector_type(8)));
typedef _Float16 half2t __attribute__((ext_vector_type(2)));
typedef float    float4t __attribute__((ext_vector_type(4)));

union U16B { float4t f4; half8 h8; float f[4]; _Float16 h[8]; half2t h2[4]; };

__device__ __forceinline__ float fast_rcp(float x){ return __builtin_amdgcn_rcpf(x); }
__device__ __forceinline__ float fast_ex2(float x){ return __builtin_amdgcn_exp2f(x); }
__device__ __forceinline__ half2t pk2(float a, float b){
    return __builtin_bit_cast(half2t, __builtin_amdgcn_cvt_pkrtz(a, b));
}

#define MFMA16(a,b,c) __builtin_amdgcn_mfma_f32_16x16x32_f16((a),(b),(c),0,0,0)

#define L2E  1.44269504f
#define L2E2 2.88539008f

// tanh table: 2048 cells over [-9,9]; sigmoid = 0.5 + 0.5*tanh(x/2)
#define TBL_N   2048
#define TBL_KT  113.777779f   // 2048/18
#define TBL_KS  56.8888893f   // KT/2 (sigmoid arg fold)
#define TBL_CEN 1024.0f
#define TBL_STEP 0.0087890625f  // 18/2048

// Unit owned by lane-quad q, tile T (q<3: 8q+T; q==3: overflow units 6,7,14,15,22,23)
__device__ __forceinline__ int unit_of(int q, int T) {
    return (q < 3) ? (8*q + T) : (8*(T >> 1) + 6 + (T & 1));
}

// Prepack fc0_w into per-timestep fp16 A-fragments (A[m=l][k=j], zeros elsewhere).
__global__ __launch_bounds__(64)
void pack_fc0(const float* __restrict__ fc0_w, float4t* __restrict__ dst)
{
    const int t = blockIdx.x, lane = threadIdx.x;
    const int m = lane & 15, q = lane >> 4;
    U16B v;
    #pragma unroll
    for (int i = 0; i < 8; ++i) {
        const int k = 8*q + i;
        float f = (m < L_ && k < H_) ? fc0_w[m*(T_*H_) + t*H_ + k] : 0.0f;
        v.h[i] = (_Float16)f;
    }
    dst[t*64 + lane] = v.f4;
}

// table lookup with linear interp: p = precomputed fractional index
__device__ __forceinline__ float tlu(const float2* __restrict__ tb, float p)
{
    p = __builtin_amdgcn_fmed3f(p, 0.0f, 2047.0f);   // clamp (1 inst)
    const float fr = __builtin_amdgcn_fractf(p);     // p - floor(p)
    const unsigned i = (unsigned)p;                  // trunc == floor (p>=0)
    const float2 e = tb[i];                          // ds_read_b64 {y, dy}
    return fmaf(fr, e.y, e.x);
}

// R17: refined model from R11-R16: trans ~16cy/wave64-inst => 42 trans/step =
// ~60% of issue demand; wave count (512) and spread (1/SIMD) are exhausted
// (R16: 2 waves/SIMD -> per-SIMD util 94%, but only 256 SIMDs). So kill the
// trans ops: one 16KB LDS tanh table (2048 float2 {y,dy} over [-9,9], lerp,
// built once/block from exp2). sigm(x)=0.5+0.5*tanh(x/2): the x0.5 folds into
// the index fma. Per act: ~6 VALU + 1 ds_read_b64 vs exp+rcp ~35cy. Demand
// ~1100 -> ~650 cy/step. Interp err <= 8e-6 (<< f16 h quantum). Rest of the
// kernel identical to R15 (best measured, 143us).
__global__ __launch_bounds__(64)
void lstm_mfma(const float* __restrict__ x,
               const float* __restrict__ W_ih,
               const float* __restrict__ W_hh,
               const float* __restrict__ b_ih,
               const float* __restrict__ b_hh,
               const float* __restrict__ fc0_b,
               const float* __restrict__ out_w,
               const float* __restrict__ out_b,
               const float4t* __restrict__ fc0A,   // prepacked in d_ws
               float* __restrict__ out)
{
    __shared__ __align__(16) float2  tanhT[TBL_N];   // 16 KB activation table
    __shared__ __align__(16) _Float16 actL[16*24];   // epilogue staging only

    const int lane = threadIdx.x;
    const int m = lane & 15;        // element col / A row-within-tile
    const int q = lane >> 4;        // quad
    const int elem = blockIdx.x * 16 + m;

    const float4t zf4 = {0.f, 0.f, 0.f, 0.f};

    // ---- build tanh table (single wave; lane-interleaved cells, no conflicts)
    #pragma unroll 1
    for (int k = 0; k < TBL_N/64; ++k) {
        const int i = k*64 + lane;
        const float x0 = fmaf((float)i, TBL_STEP, -9.0f);
        const float x1 = x0 + TBL_STEP;
        const float e0 = fast_ex2(x0 * L2E2);               // e^{2*x0}
        const float e1 = fast_ex2(x1 * L2E2);
        const float y0 = 1.0f - 2.0f * fast_rcp(e0 + 1.0f); // tanh(x0)
        const float y1 = 1.0f - 2.0f * fast_rcp(e1 + 1.0f);
        tanhT[i] = make_float2(y0, y1 - y0);
    }

    // ---- gate A-fragments ----
    half8 Ag[6];
    #pragma unroll
    for (int T6 = 0; T6 < 6; ++T6) {
        const int u = unit_of(m >> 2, T6);
        const int srow = (m & 3) * H_ + u;       // torch gate-major row
        float wv[8];
        if (q < 3) {
            const float4t* pw = (const float4t*)(W_hh + srow*H_ + 8*q);
            float4t wa = pw[0], wb = pw[1];
            #pragma unroll
            for (int i = 0; i < 4; ++i) { wv[i] = wa[i]; wv[4+i] = wb[i]; }
        } else {
            #pragma unroll
            for (int i = 0; i < 8; ++i) wv[i] = 0.f;
            #pragma unroll
            for (int i = 0; i < I_; ++i) wv[i] = W_ih[srow*I_ + i];
            wv[5] = b_ih[srow] + b_hh[srow];
        }
        U16B tw;
        #pragma unroll
        for (int i = 0; i < 8; ++i) tw.h[i] = (_Float16)wv[i];
        Ag[T6] = tw.h8;
    }

    const float* xp = x + (size_t)elem * (T_*I_);

    // ---- initial B-frag [h=0 | x_0 | 1 | 0,0]; x prefetch ring (depth 2) ----
    U16B B;
    if (q == 3) {
        B.h2[0] = pk2(xp[0], xp[1]);
        B.h2[1] = pk2(xp[2], xp[3]);
        B.h2[2] = pk2(xp[4], 1.0f);
        B.h2[3] = pk2(0.f, 0.f);
    } else {
        B.f4 = zf4;
    }
    float xC[I_] = {0,0,0,0,0};              // x(t+1), consumed at iter bottom
    if (q == 3) {
        #pragma unroll
        for (int i = 0; i < I_; ++i) xC[i] = xp[I_ + i];
    }

    float c_[6] = {0,0,0,0,0,0};
    float4t accF = zf4;
    float4t fa = fc0A[lane];                 // fc0 frag for t=0

    // table writes must land before first lookups (same wave: lgkm only)
    asm volatile("s_waitcnt lgkmcnt(0)" ::: "memory");

    // ================= time loop (no barriers, shuffle exchange) ===========
    for (int t = 0; t < T_; ++t) {
        // prefetches: x(t+2), fc0 frag t+1
        const int tn = (t + 1 < T_) ? t + 1 : t;
        const float4t fan = fc0A[tn*64 + lane];
        float xN[I_] = {0,0,0,0,0};
        if (q == 3) {
            const int tp2 = (t + 2 < T_) ? t + 2 : T_ - 1;
            const float* xq = xp + tp2*I_;
            #pragma unroll
            for (int i = 0; i < I_; ++i) xN[i] = xq[i];
        }

        // 6 gate MFMAs
        float4t D0 = MFMA16(Ag[0], B.h8, zf4);
        float4t D1 = MFMA16(Ag[1], B.h8, zf4);
        float4t D2 = MFMA16(Ag[2], B.h8, zf4);
        float4t D3 = MFMA16(Ag[3], B.h8, zf4);
        float4t D4 = MFMA16(Ag[4], B.h8, zf4);
        float4t D5 = MFMA16(Ag[5], B.h8, zf4);

        // table-based cell update, phase-interleaved across 6 units
        float hh[6];
        {
            float4t D[6] = {D0, D1, D2, D3, D4, D5};
            float yi[6], yf[6], yg[6], yo[6];
            #pragma unroll
            for (int u = 0; u < 6; ++u) {
                yi[u] = tlu(tanhT, fmaf(D[u][0], TBL_KS, TBL_CEN)); // tanh(i/2)
                yf[u] = tlu(tanhT, fmaf(D[u][1], TBL_KS, TBL_CEN)); // tanh(f/2)
                yg[u] = tlu(tanhT, fmaf(D[u][2], TBL_KT, TBL_CEN)); // tanh(g)
                yo[u] = tlu(tanhT, fmaf(D[u][3], TBL_KS, TBL_CEN)); // tanh(o/2)
            }
            float th[6];
            #pragma unroll
            for (int u = 0; u < 6; ++u) {
                const float si = fmaf(0.5f, yi[u], 0.5f);
                const float sf = fmaf(0.5f, yf[u], 0.5f);
                c_[u] = fmaf(sf, c_[u], si * yg[u]);
                th[u] = tlu(tanhT, fmaf(c_[u], TBL_KT, TBL_CEN));   // tanh(c')
            }
            #pragma unroll
            for (int u = 0; u < 6; ++u) {
                const float so = fmaf(0.5f, yo[u], 0.5f);
                hh[u] = so * th[u];
            }
        }

        // pack own h pairs; q3's pairs are the overflow units consumers need
        const float P0 = __builtin_bit_cast(float, pk2(hh[0], hh[1]));
        const float P1 = __builtin_bit_cast(float, pk2(hh[2], hh[3]));
        const float P2 = __builtin_bit_cast(float, pk2(hh[4], hh[5]));

        // fetch overflow pair from lane (m, q=3) = lane 48+m (3 bpermutes)
        const int src = 48 + m;
        const float r0 = __shfl(P0, src, 64);
        const float r1 = __shfl(P1, src, 64);
        const float r2 = __shfl(P2, src, 64);
        const float rcv = (q == 0) ? r0 : ((q == 1) ? r1 : r2);

        // rebuild B-frag
        if (q < 3) {
            B.h2[0] = __builtin_bit_cast(half2t, P0);   // units 8q+0,1
            B.h2[1] = __builtin_bit_cast(half2t, P1);   // units 8q+2,3
            B.h2[2] = __builtin_bit_cast(half2t, P2);   // units 8q+4,5
            B.h2[3] = __builtin_bit_cast(half2t, rcv);  // units 8q+6,7 (from q3)
        } else {
            B.h2[0] = pk2(xC[0], xC[1]);
            B.h2[1] = pk2(xC[2], xC[3]);
            B.h2[2] = pk2(xC[4], 1.0f);
            B.h2[3] = pk2(0.f, 0.f);
        }

        // fc0 accumulation with h_t (fc0A rows k>=24 are zero)
        U16B fF; fF.f4 = fa;
        accF = MFMA16(fF.h8, B.h8, accF);

        fa = fan;
        #pragma unroll
        for (int i = 0; i < I_; ++i) xC[i] = xN[i];
    }

    // ================= epilogue (validated R7/R8) =================
    float av[4];
    #pragma unroll
    for (int r = 0; r < 4; ++r) {
        const int l = 4*q + r;
        const float fb = (l < L_) ? fc0_b[l] : 0.f;
        const float v = accF[r] + fb;
        av[r] = (l < L_) ? fmaxf(v, 0.f) : 0.f;
    }
    *(half2t*)(&actL[m*24 + 4*q])     = pk2(av[0], av[1]);
    *(half2t*)(&actL[m*24 + 4*q + 2]) = pk2(av[2], av[3]);
    __builtin_amdgcn_wave_barrier();

    U16B Ba;
    if (q < 2) Ba.f4 = *(const float4t*)(&actL[m*24 + q*8]);
    else       Ba.f4 = zf4;            // k>=16 unused (out_w A-frag zero there)

    for (int Tt = 0; Tt < 39; ++Tt) {
        const int row = 16*Tt + m;
        float w0=0.f,w1=0.f,w2=0.f,w3=0.f,w4=0.f,w5=0.f,w6=0.f,w7=0.f;
        if (row < O_ && q < 2) {
            const float2* p2 = (const float2*)(out_w + row*L_);
            if (q == 0) {
                float2 a = p2[0], b = p2[1], cc = p2[2], dd = p2[3];
                w0=a.x; w1=a.y; w2=b.x; w3=b.y; w4=cc.x; w5=cc.y; w6=dd.x; w7=dd.y;
            } else {
                float2 a = p2[4];
                w0=a.x; w1=a.y;
            }
        }
        U16B Aw;
        Aw.h2[0] = pk2(w0,w1); Aw.h2[1] = pk2(w2,w3);
        Aw.h2[2] = pk2(w4,w5); Aw.h2[3] = pk2(w6,w7);

        float4t dd = MFMA16(Aw.h8, Ba.h8, zf4);

        const int ob = 16*Tt + 4*q;
        if (ob < O_) {
            const float4t bias = *(const float4t*)(out_b + ob);
            #pragma unroll
            for (int r = 0; r < 4; ++r) dd[r] += bias[r];
            *(float4t*)(out + (size_t)elem*O_ + ob) = dd;
        }
    }
}

extern "C" void kernel_launch(void* const* d_in, const int* in_sizes, int n_in,
                              void* d_out, int out_size, void* d_ws, size_t ws_size,
                              hipStream_t stream)
{
    const float* x     = (const float*)d_in[0];
    const float* W_ih  = (const float*)d_in[1];
    const float* W_hh  = (const float*)d_in[2];
    const float* b_ih  = (const float*)d_in[3];
    const float* b_hh  = (const float*)d_in[4];
    const float* fc0_w = (const float*)d_in[5];
    const float* fc0_b = (const float*)d_in[6];
    const float* out_w = (const float*)d_in[7];
    const float* out_b = (const float*)d_in[8];
    float* out = (float*)d_out;
    (void)ws_size;

    pack_fc0<<<dim3(T_), dim3(64), 0, stream>>>(fc0_w, (float4t*)d_ws);
    lstm_mfma<<<dim3(Bsz/16), dim3(64), 0, stream>>>(
        x, W_ih, W_hh, b_ih, b_hh, fc0_b, out_w, out_b,
        (const float4t*)d_ws, out);
}

// Round 7
// 214.536 us; speedup vs baseline: 1.2907x; 1.2742x over previous
//
#include <hip/hip_runtime.h>
#include <math.h>

// Problem constants
#define T_  204
#define I_  5
#define H_  24
#define L_  10
#define O_  612
#define Bsz 8192

typedef _Float16 half8 __attribute__((ext_vector_type(8)));
typedef _Float16 half2t __attribute__((ext_vector_type(2)));
typedef float    float4t __attribute__((ext_vector_type(4)));

union U16B { float4t f4; half8 h8; float f[4]; _Float16 h[8]; half2t h2[4]; };

__device__ __forceinline__ float fast_rcp(float x){ return __builtin_amdgcn_rcpf(x); }
__device__ __forceinline__ float fast_ex2(float x){ return __builtin_amdgcn_exp2f(x); }
__device__ __forceinline__ half2t pk2(float a, float b){
    return __builtin_bit_cast(half2t, __builtin_amdgcn_cvt_pkrtz(a, b));
}

#define MFMA16(a,b,c) __builtin_amdgcn_mfma_f32_16x16x32_f16((a),(b),(c),0,0,0)

#define L2E  1.44269504f
#define L2E2 2.88539008f

// Unit owned by lane-quad q, tile T (q<3: 8q+T; q==3: overflow units 6,7,14,15,22,23)
__device__ __forceinline__ int unit_of(int q, int T) {
    return (q < 3) ? (8*q + T) : (8*(T >> 1) + 6 + (T & 1));
}

// Prepack fc0_w into per-timestep fp16 A-fragments (A[m=l][k=j], zeros elsewhere).
__global__ __launch_bounds__(64)
void pack_fc0(const float* __restrict__ fc0_w, float4t* __restrict__ dst)
{
    const int t = blockIdx.x, lane = threadIdx.x;
    const int m = lane & 15, q = lane >> 4;
    U16B v;
    #pragma unroll
    for (int i = 0; i < 8; ++i) {
        const int k = 8*q + i;
        float f = (m < L_ && k < H_) ? fc0_w[m*(T_*H_) + t*H_ + k] : 0.0f;
        v.h[i] = (_Float16)f;
    }
    dst[t*64 + lane] = v.f4;
}

// R15 fused-denominator activation, per unit (bitwise-identical results):
//   c' = [c*Dn2*Dn3 + Dn1*(e2g-1)] * rcp(Dn1*Dn2*Dn3)
//   h  = copysign((1-es)*rcp((1+e^-o)(1+es)), c'), es = e^{-2|c'|}
#define ACT1(Dv, cc, hh)                                                        \
  {                                                                             \
    const float ei = fast_ex2((Dv)[0] * -L2E);                                  \
    const float ef = fast_ex2((Dv)[1] * -L2E);                                  \
    const float eg = fast_ex2((Dv)[2] *  L2E2);                                 \
    const float eo = fast_ex2((Dv)[3] * -L2E);                                  \
    const float Dn1 = 1.f + ef;                                                 \
    const float Dn2 = 1.f + ei;                                                 \
    const float Dn3 = eg + 1.f;                                                 \
    const float G   = eg - 1.f;                                                 \
    const float P   = Dn2 * Dn3;                                                \
    const float R1  = fast_rcp(Dn1 * P);                                        \
    const float nm  = fmaf((cc), P, Dn1 * G);                                   \
    (cc) = nm * R1;                                                             \
    const float es  = fast_ex2(__builtin_fabsf(cc) * -L2E2);                    \
    const float R2  = fast_rcp((1.f + eo) * (1.f + es));                        \
    (hh) = __builtin_copysignf((1.f - es) * R2, (cc));                          \
  }

// R18: R17's LDS table failed on bank conflicts (3K -> 8.18M) -- reverted to
// R15 structure. R15 residual: ~975 busy + ~700 stall cy/step. Provable stall
// source: the loop-bottom copies fa=fan / xC=xN force the vmcnt wait into the
// SAME iteration the load issued (~1-body shadow vs 200-900cy latency). Fix:
// 204 = 4x51 -> full 4x unroll with NAMED slots fa0..3 / xs0..3, slot k
// reloaded right after its consumption for step t+k+4 => copy-free depth-4
// ring, ~4-step vmcnt shadow. Plus VALU slim: act written straight off D0..D5
// (no D[6] staging array). Math identical to R15 (absmax 0.001953125).
#define POS(K, faK, xsK)                                                        \
  {                                                                             \
    float4t D0 = MFMA16(Ag[0], B.h8, zf4);                                      \
    float4t D1 = MFMA16(Ag[1], B.h8, zf4);                                      \
    float4t D2 = MFMA16(Ag[2], B.h8, zf4);                                      \
    float4t D3 = MFMA16(Ag[3], B.h8, zf4);                                      \
    float4t D4 = MFMA16(Ag[4], B.h8, zf4);                                      \
    float4t D5 = MFMA16(Ag[5], B.h8, zf4);                                      \
    float hh0, hh1, hh2, hh3, hh4, hh5;                                         \
    ACT1(D0, c0, hh0)                                                           \
    ACT1(D1, c1, hh1)                                                           \
    ACT1(D2, c2, hh2)                                                           \
    ACT1(D3, c3, hh3)                                                           \
    ACT1(D4, c4, hh4)                                                           \
    ACT1(D5, c5, hh5)                                                           \
    const float P0 = __builtin_bit_cast(float, pk2(hh0, hh1));                  \
    const float P1 = __builtin_bit_cast(float, pk2(hh2, hh3));                  \
    const float P2 = __builtin_bit_cast(float, pk2(hh4, hh5));                  \
    const float r0 = __shfl(P0, src, 64);                                       \
    const float r1 = __shfl(P1, src, 64);                                       \
    const float r2 = __shfl(P2, src, 64);                                       \
    const float rcv = (q == 0) ? r0 : ((q == 1) ? r1 : r2);                     \
    if (q < 3) {                                                                \
      B.h2[0] = __builtin_bit_cast(half2t, P0);                                 \
      B.h2[1] = __builtin_bit_cast(half2t, P1);                                 \
      B.h2[2] = __builtin_bit_cast(half2t, P2);                                 \
      B.h2[3] = __builtin_bit_cast(half2t, rcv);                                \
    } else {                                                                    \
      B.h2[0] = pk2(xsK[0], xsK[1]);                                            \
      B.h2[1] = pk2(xsK[2], xsK[3]);                                            \
      B.h2[2] = pk2(xsK[4], 1.0f);                                              \
      B.h2[3] = pk2(0.f, 0.f);                                                  \
    }                                                                           \
    { U16B fF; fF.f4 = faK;                                                     \
      accF = MFMA16(fF.h8, B.h8, accF); }                                       \
    /* slot reloads: consumed again at step t+K+4 (4-step vmcnt shadow) */      \
    { const int tf = (t + K + 4 < T_) ? t + K + 4 : T_ - 1;                     \
      faK = fc0A[tf*64 + lane]; }                                               \
    if (q == 3) {                                                               \
      const int txi = (t + K + 5 < T_) ? t + K + 5 : T_ - 1;                    \
      const float* xq = xp + txi*I_;                                            \
      _Pragma("unroll")                                                         \
      for (int i = 0; i < I_; ++i) xsK[i] = xq[i];                              \
    }                                                                           \
  }

__global__ __launch_bounds__(64)
void lstm_mfma(const float* __restrict__ x,
               const float* __restrict__ W_ih,
               const float* __restrict__ W_hh,
               const float* __restrict__ b_ih,
               const float* __restrict__ b_hh,
               const float* __restrict__ fc0_b,
               const float* __restrict__ out_w,
               const float* __restrict__ out_b,
               const float4t* __restrict__ fc0A,   // prepacked in d_ws
               float* __restrict__ out)
{
    __shared__ __align__(16) _Float16 actL[16*24];  // epilogue staging only

    const int lane = threadIdx.x;
    const int m = lane & 15;        // element col / A row-within-tile
    const int q = lane >> 4;        // quad
    const int elem = blockIdx.x * 16 + m;
    const int src = 48 + m;         // bpermute source lane (q3 overflow pairs)

    const float4t zf4 = {0.f, 0.f, 0.f, 0.f};

    // ---- gate A-fragments ----
    half8 Ag[6];
    #pragma unroll
    for (int T6 = 0; T6 < 6; ++T6) {
        const int u = unit_of(m >> 2, T6);
        const int srow = (m & 3) * H_ + u;       // torch gate-major row
        float wv[8];
        if (q < 3) {
            const float4t* pw = (const float4t*)(W_hh + srow*H_ + 8*q);
            float4t wa = pw[0], wb = pw[1];
            #pragma unroll
            for (int i = 0; i < 4; ++i) { wv[i] = wa[i]; wv[4+i] = wb[i]; }
        } else {
            #pragma unroll
            for (int i = 0; i < 8; ++i) wv[i] = 0.f;
            #pragma unroll
            for (int i = 0; i < I_; ++i) wv[i] = W_ih[srow*I_ + i];
            wv[5] = b_ih[srow] + b_hh[srow];
        }
        U16B tw;
        #pragma unroll
        for (int i = 0; i < 8; ++i) tw.h[i] = (_Float16)wv[i];
        Ag[T6] = tw.h8;
    }

    const float* xp = x + (size_t)elem * (T_*I_);

    // ---- initial B-frag [h=0 | x_0 | 1 | 0,0] ----
    U16B B;
    if (q == 3) {
        B.h2[0] = pk2(xp[0], xp[1]);
        B.h2[1] = pk2(xp[2], xp[3]);
        B.h2[2] = pk2(xp[4], 1.0f);
        B.h2[3] = pk2(0.f, 0.f);
    } else {
        B.f4 = zf4;
    }

    // ---- depth-4 prefetch ring, named slots (slot k: data for step t0+k) ----
    float4t fa0 = fc0A[0*64 + lane];
    float4t fa1 = fc0A[1*64 + lane];
    float4t fa2 = fc0A[2*64 + lane];
    float4t fa3 = fc0A[3*64 + lane];
    float xs0[I_] = {0,0,0,0,0}, xs1[I_] = {0,0,0,0,0};
    float xs2[I_] = {0,0,0,0,0}, xs3[I_] = {0,0,0,0,0};
    if (q == 3) {
        #pragma unroll
        for (int i = 0; i < I_; ++i) {
            xs0[i] = xp[1*I_ + i];   // x(1) consumed at t=0
            xs1[i] = xp[2*I_ + i];
            xs2[i] = xp[3*I_ + i];
            xs3[i] = xp[4*I_ + i];
        }
    }

    float c0 = 0.f, c1 = 0.f, c2 = 0.f, c3 = 0.f, c4 = 0.f, c5 = 0.f;
    float4t accF = zf4;

    // ================= time loop: 51 x 4 steps, copy-free ring =============
    #pragma unroll 1
    for (int t = 0; t < T_; t += 4) {
        POS(0, fa0, xs0)
        POS(1, fa1, xs1)
        POS(2, fa2, xs2)
        POS(3, fa3, xs3)
    }

    // ================= epilogue (validated R7/R8) =================
    float av[4];
    #pragma unroll
    for (int r = 0; r < 4; ++r) {
        const int l = 4*q + r;
        const float fb = (l < L_) ? fc0_b[l] : 0.f;
        const float v = accF[r] + fb;
        av[r] = (l < L_) ? fmaxf(v, 0.f) : 0.f;
    }
    *(half2t*)(&actL[m*24 + 4*q])     = pk2(av[0], av[1]);
    *(half2t*)(&actL[m*24 + 4*q + 2]) = pk2(av[2], av[3]);
    __builtin_amdgcn_wave_barrier();

    U16B Ba;
    if (q < 2) Ba.f4 = *(const float4t*)(&actL[m*24 + q*8]);
    else       Ba.f4 = zf4;            // k>=16 unused (out_w A-frag zero there)

    for (int Tt = 0; Tt < 39; ++Tt) {
        const int row = 16*Tt + m;
        float w0=0.f,w1=0.f,w2=0.f,w3=0.f,w4=0.f,w5=0.f,w6=0.f,w7=0.f;
        if (row < O_ && q < 2) {
            const float2* p2 = (const float2*)(out_w + row*L_);
            if (q == 0) {
                float2 a = p2[0], b = p2[1], cc = p2[2], dd = p2[3];
                w0=a.x; w1=a.y; w2=b.x; w3=b.y; w4=cc.x; w5=cc.y; w6=dd.x; w7=dd.y;
            } else {
                float2 a = p2[4];
                w0=a.x; w1=a.y;
            }
        }
        U16B Aw;
        Aw.h2[0] = pk2(w0,w1); Aw.h2[1] = pk2(w2,w3);
        Aw.h2[2] = pk2(w4,w5); Aw.h2[3] = pk2(w6,w7);

        float4t dd = MFMA16(Aw.h8, Ba.h8, zf4);

        const int ob = 16*Tt + 4*q;
        if (ob < O_) {
            const float4t bias = *(const float4t*)(out_b + ob);
            #pragma unroll
            for (int r = 0; r < 4; ++r) dd[r] += bias[r];
            *(float4t*)(out + (size_t)elem*O_ + ob) = dd;
        }
    }
}

extern "C" void kernel_launch(void* const* d_in, const int* in_sizes, int n_in,
                              void* d_out, int out_size, void* d_ws, size_t ws_size,
                              hipStream_t stream)
{
    const float* x     = (const float*)d_in[0];
    const float* W_ih  = (const float*)d_in[1];
    const float* W_hh  = (const float*)d_in[2];
    const float* b_ih  = (const float*)d_in[3];
    const float* b_hh  = (const float*)d_in[4];
    const float* fc0_w = (const float*)d_in[5];
    const float* fc0_b = (const float*)d_in[6];
    const float* out_w = (const float*)d_in[7];
    const float* out_b = (const float*)d_in[8];
    float* out = (float*)d_out;
    (void)ws_size;

    pack_fc0<<<dim3(T_), dim3(64), 0, stream>>>(fc0_w, (float4t*)d_ws);
    lstm_mfma<<<dim3(Bsz/16), dim3(64), 0, stream>>>(
        x, W_ih, W_hh, b_ih, b_hh, fc0_b, out_w, out_b,
        (const float4t*)d_ws, out);
}